// Round 4
// baseline (1578.810 us; speedup 1.0000x reference)
//
#include <hip/hip_runtime.h>
#include <hip/hip_bf16.h>
#include <cstdint>
#include <cstddef>

// Problem constants (from reference)
#define T_TOK 4096
#define DM    1024
#define DF    2048
#define FS    4096
#define NE    8
#define NCAT    20480   // 8*2048 expert cols + 4096 shared cols
#define NEXPCOL 16384   // boundary: cols < this are expert cols
#define KSPLIT  5       // down-GEMM K split (NCAT/KSPLIT = 4096)
#define KCH     4096

typedef __attribute__((ext_vector_type(8))) short  s16x8;   // 8 x bf16 (4 VGPRs)
typedef __attribute__((ext_vector_type(4))) float  f32x4;
typedef unsigned short u16;

// ---------------- helpers ----------------
__device__ __forceinline__ u16 f2bf(float f) {
  unsigned u = __builtin_bit_cast(unsigned, f);
  unsigned r = u + 0x7fffu + ((u >> 16) & 1u);   // RNE
  return (u16)(r >> 16);
}

__device__ __forceinline__ float silu_prod(float a, float b) {
  float z = a * b;
  return z / (1.f + __expf(-z));
}

__device__ __forceinline__ void load_lds16(const u16* g, u16* l) {
  __builtin_amdgcn_global_load_lds(
      (const __attribute__((address_space(1))) unsigned int*)g,
      (__attribute__((address_space(3))) unsigned int*)l,
      16, 0, 0);
}

// ---------------- x -> bf16 ----------------
__global__ __launch_bounds__(256) void cvt_bf16(const float* __restrict__ in,
                                                u16* __restrict__ out, int n4) {
  int i = blockIdx.x * 256 + threadIdx.x;
  if (i >= n4) return;
  float4 v = ((const float4*)in)[i];
  ushort4 o;
  o.x = f2bf(v.x); o.y = f2bf(v.y); o.z = f2bf(v.z); o.w = f2bf(v.w);
  ((ushort4*)out)[i] = o;
}

// ---------------- batched transpose+convert ----------------
// in[z][R][C] f32  ->  out[(c + z*zr)*ldo + z*zc + r] bf16   (out row c, col r)
__global__ __launch_bounds__(256) void tconv2(const float* __restrict__ in,
                                              u16* __restrict__ out,
                                              int R, int C, int ldo, int zr, int zc) {
  __shared__ float tile[32][33];
  const int z = blockIdx.z;
  in += (size_t)z * R * C;
  int c0 = blockIdx.x * 32, r0 = blockIdx.y * 32;
  int tx = threadIdx.x & 31, ty = threadIdx.x >> 5;  // 32 x 8
#pragma unroll
  for (int i = ty; i < 32; i += 8)
    tile[i][tx] = in[(size_t)(r0 + i) * C + (c0 + tx)];
  __syncthreads();
#pragma unroll
  for (int i = ty; i < 32; i += 8)
    out[(size_t)(c0 + i + z * zr) * ldo + z * zc + (r0 + tx)] = f2bf(tile[tx][i]);
}

// ---------------- gating: exact fp32 softmax -> top2 -> softmax weights ----------------
__global__ __launch_bounds__(256) void gating_kernel(const float* __restrict__ x,
                                                     const float* __restrict__ Wg,
                                                     float* __restrict__ comb) {
  int t = blockIdx.x * 4 + (threadIdx.x >> 6);
  int lane = threadIdx.x & 63;
  float p[NE];
#pragma unroll
  for (int e = 0; e < NE; e++) p[e] = 0.f;
  const float* xr = x + (size_t)t * DM;
  for (int d = lane; d < DM; d += 64) {
    float xv = xr[d];
    const float* wr = Wg + (size_t)d * NE;
#pragma unroll
    for (int e = 0; e < NE; e++) p[e] += xv * wr[e];
  }
#pragma unroll
  for (int off = 32; off > 0; off >>= 1) {
#pragma unroll
    for (int e = 0; e < NE; e++) p[e] += __shfl_xor(p[e], off, 64);
  }
  if (lane == 0) {
    float m = p[0];
#pragma unroll
    for (int e = 1; e < NE; e++) m = fmaxf(m, p[e]);
    float sc[NE]; float s = 0.f;
#pragma unroll
    for (int e = 0; e < NE; e++) { sc[e] = expf(p[e] - m); s += sc[e]; }
    float inv = 1.f / s;
#pragma unroll
    for (int e = 0; e < NE; e++) sc[e] *= inv;
    // top-2, ties -> lower index (matches lax.top_k)
    int i1 = 0; float v1 = sc[0];
#pragma unroll
    for (int e = 1; e < NE; e++) if (sc[e] > v1) { v1 = sc[e]; i1 = e; }
    int i2 = -1; float v2 = -1.f;
#pragma unroll
    for (int e = 0; e < NE; e++) if (e != i1 && sc[e] > v2) { v2 = sc[e]; i2 = e; }
    // renormalize: softmax over the two selected scores
    float w2 = 1.f / (1.f + expf(v1 - v2));
    float w1 = 1.f - w2;
    float* cr = comb + (size_t)t * NE;
#pragma unroll
    for (int e = 0; e < NE; e++) cr[e] = (e == i1) ? w1 : ((e == i2) ? w2 : 0.f);
  }
}

// ---------------- fused dual up-GEMM + silu + comb-scale ----------------
// act[M x NCAT](bf16) = cw(n) * silu( (A*B1^T + b1) .* (A*B3^T + b3) )
// A:[M x 1024] bf16; B1,B3:[NCAT x 1024] bf16 row-major; cw = comb[t, n>>11] for
// n < NEXPCOL else 1.  m97 128^2-tile structure, K = 1024.
__global__ __launch_bounds__(256) void gemm_up_silu(const u16* __restrict__ A,
                                                    const u16* __restrict__ B1,
                                                    const u16* __restrict__ B3,
                                                    const float* __restrict__ bias1,
                                                    const float* __restrict__ bias3,
                                                    const float* __restrict__ comb,
                                                    u16* __restrict__ act) {
  __shared__ u16 sA[128 * 32];
  __shared__ u16 sB1[128 * 32];
  __shared__ u16 sB3[128 * 32];
  const int K    = DM;
  const int tid  = threadIdx.x;
  const int m0   = blockIdx.y * 128;
  const int n0   = blockIdx.x * 128;
  const int lane = tid & 63;
  const int w    = tid >> 6;
  const int wr   = (w >> 1) * 64;
  const int wc   = (w & 1) * 64;
  const int fr   = lane & 15;
  const int fq   = lane >> 4;

  f32x4 acc1[4][4] = {};
  f32x4 acc3[4][4] = {};

  const int li0 = tid * 8;                  // element index in 128x32 tile
  const u16* gA0  = A  + (size_t)(m0 + (li0 >> 5)) * K + (li0 & 31);
  const u16* gB10 = B1 + (size_t)(n0 + (li0 >> 5)) * K + (li0 & 31);
  const u16* gB30 = B3 + (size_t)(n0 + (li0 >> 5)) * K + (li0 & 31);
  const size_t rowskip = (size_t)64 * K;    // chunk1 = +64 rows
  u16* lA0  = sA  + ((tid & 192) << 3);     // wave-uniform LDS base
  u16* lB10 = sB1 + ((tid & 192) << 3);
  u16* lB30 = sB3 + ((tid & 192) << 3);

  for (int k0 = 0; k0 < K; k0 += 32) {
    load_lds16(gA0  + k0,           lA0);
    load_lds16(gA0  + k0 + rowskip, lA0 + 2048);
    load_lds16(gB10 + k0,           lB10);
    load_lds16(gB10 + k0 + rowskip, lB10 + 2048);
    load_lds16(gB30 + k0,           lB30);
    load_lds16(gB30 + k0 + rowskip, lB30 + 2048);
    __syncthreads();

    s16x8 af[4], b1f[4], b3f[4];
#pragma unroll
    for (int m = 0; m < 4; m++)
      af[m] = *(const s16x8*)(sA + (wr + m * 16 + fr) * 32 + fq * 8);
#pragma unroll
    for (int n = 0; n < 4; n++) {
      b1f[n] = *(const s16x8*)(sB1 + (wc + n * 16 + fr) * 32 + fq * 8);
      b3f[n] = *(const s16x8*)(sB3 + (wc + n * 16 + fr) * 32 + fq * 8);
    }
#pragma unroll
    for (int m = 0; m < 4; m++)
#pragma unroll
      for (int n = 0; n < 4; n++) {
        acc1[m][n] = __builtin_amdgcn_mfma_f32_16x16x32_bf16(af[m], b1f[n], acc1[m][n], 0, 0, 0);
        acc3[m][n] = __builtin_amdgcn_mfma_f32_16x16x32_bf16(af[m], b3f[n], acc3[m][n], 0, 0, 0);
      }
    __syncthreads();
  }

  // expert id for this column block (128-tile never straddles a 2048 boundary)
  const bool isExp = (n0 < NEXPCOL);
  const int  eid   = n0 >> 11;

  // C/D layout (m89-verified): col = lane&15, row = (lane>>4)*4 + j
#pragma unroll
  for (int m = 0; m < 4; m++) {
#pragma unroll
    for (int n = 0; n < 4; n++) {
      int cc = n0 + wc + n * 16 + fr;
      float c1 = bias1[cc], c3 = bias3[cc];
#pragma unroll
      for (int j = 0; j < 4; j++) {
        int r = m0 + wr + m * 16 + fq * 4 + j;
        float wgt = isExp ? comb[(size_t)r * NE + eid] : 1.f;
        float v = wgt * silu_prod(acc1[m][n][j] + c1, acc3[m][n][j] + c3);
        act[(size_t)r * NCAT + cc] = f2bf(v);
      }
    }
  }
}

// ---------------- down GEMM, K-split ----------------
// partial[z][M x 1024] = A[M x NCAT](cols z*4096..+4096) * B^T(same K range)
// z = blockIdx.z.  No bias here (reduce kernel applies it).
__global__ __launch_bounds__(256) void gemm_down(const u16* __restrict__ A,
                                                 const u16* __restrict__ B,
                                                 float* __restrict__ partial,
                                                 int Mchunk) {
  __shared__ u16 sA[128 * 32];
  __shared__ u16 sB[128 * 32];
  const int tid  = threadIdx.x;
  const int m0   = blockIdx.y * 128;
  const int n0   = blockIdx.x * 128;
  const int z    = blockIdx.z;
  const int lane = tid & 63;
  const int w    = tid >> 6;
  const int wr   = (w >> 1) * 64;
  const int wc   = (w & 1) * 64;
  const int fr   = lane & 15;
  const int fq   = lane >> 4;

  f32x4 acc[4][4] = {};

  const int li0 = tid * 8;
  const size_t zoff = (size_t)z * KCH;
  const u16* gA0 = A + (size_t)(m0 + (li0 >> 5)) * NCAT + zoff + (li0 & 31);
  const u16* gB0 = B + (size_t)(n0 + (li0 >> 5)) * NCAT + zoff + (li0 & 31);
  const size_t rowskip = (size_t)64 * NCAT;
  u16* lA0 = sA + ((tid & 192) << 3);
  u16* lB0 = sB + ((tid & 192) << 3);

  for (int k0 = 0; k0 < KCH; k0 += 32) {
    load_lds16(gA0 + k0,           lA0);
    load_lds16(gA0 + k0 + rowskip, lA0 + 2048);
    load_lds16(gB0 + k0,           lB0);
    load_lds16(gB0 + k0 + rowskip, lB0 + 2048);
    __syncthreads();

    s16x8 af[4], bfr[4];
#pragma unroll
    for (int m = 0; m < 4; m++)
      af[m] = *(const s16x8*)(sA + (wr + m * 16 + fr) * 32 + fq * 8);
#pragma unroll
    for (int n = 0; n < 4; n++)
      bfr[n] = *(const s16x8*)(sB + (wc + n * 16 + fr) * 32 + fq * 8);
#pragma unroll
    for (int m = 0; m < 4; m++)
#pragma unroll
      for (int n = 0; n < 4; n++)
        acc[m][n] = __builtin_amdgcn_mfma_f32_16x16x32_bf16(af[m], bfr[n], acc[m][n], 0, 0, 0);
    __syncthreads();
  }

  float* P = partial + (size_t)z * Mchunk * DM;
#pragma unroll
  for (int m = 0; m < 4; m++) {
#pragma unroll
    for (int n = 0; n < 4; n++) {
      int cc = n0 + wc + n * 16 + fr;
#pragma unroll
      for (int j = 0; j < 4; j++) {
        int r = m0 + wr + m * 16 + fq * 4 + j;
        P[(size_t)r * DM + cc] = acc[m][n][j];
      }
    }
  }
}

// ---------------- reduce partials + gated bias ----------------
// out[t][d] = sum_z partial[z][tl][d] + sum_e comb[t,e]*b2[e,d] + bs2[d]
__global__ __launch_bounds__(256) void reduce_down(const float* __restrict__ partial,
                                                   float* __restrict__ out,
                                                   const float* __restrict__ comb,
                                                   const float* __restrict__ b2,
                                                   const float* __restrict__ bs2,
                                                   int Mchunk) {
  int i = blockIdx.x * 256 + threadIdx.x;         // float4 index over Mchunk*DM/4
  if (i >= Mchunk * (DM / 4)) return;
  int tl = i / (DM / 4);
  int d4 = (i % (DM / 4)) * 4;
  const size_t stride = (size_t)Mchunk * DM;
  float4 s = ((const float4*)partial)[i];
#pragma unroll
  for (int z = 1; z < KSPLIT; z++) {
    float4 p = *(const float4*)(partial + (size_t)z * stride + (size_t)tl * DM + d4);
    s.x += p.x; s.y += p.y; s.z += p.z; s.w += p.w;
  }
  float4 bsh = *(const float4*)(bs2 + d4);
  s.x += bsh.x; s.y += bsh.y; s.z += bsh.z; s.w += bsh.w;
  const float* cr = comb + (size_t)tl * NE;
#pragma unroll
  for (int e = 0; e < NE; e++) {
    float cw = cr[e];
    float4 bb = *(const float4*)(b2 + (size_t)e * DM + d4);
    s.x += cw * bb.x; s.y += cw * bb.y; s.z += cw * bb.z; s.w += cw * bb.w;
  }
  ((float4*)out)[i] = s;
}

// ---------------- host ----------------
extern "C" void kernel_launch(void* const* d_in, const int* in_sizes, int n_in,
                              void* d_out, int out_size, void* d_ws, size_t ws_size,
                              hipStream_t stream) {
  const float* x   = (const float*)d_in[0];
  const float* Wg  = (const float*)d_in[1];
  const float* W1  = (const float*)d_in[2];
  const float* b1  = (const float*)d_in[3];
  const float* W3  = (const float*)d_in[4];
  const float* b3  = (const float*)d_in[5];
  const float* W2  = (const float*)d_in[6];
  const float* b2  = (const float*)d_in[7];
  const float* Ws1 = (const float*)d_in[8];
  const float* bs1 = (const float*)d_in[9];
  const float* Ws3 = (const float*)d_in[10];
  const float* bs3 = (const float*)d_in[11];
  const float* Ws2 = (const float*)d_in[12];
  const float* bs2 = (const float*)d_in[13];
  float* out = (float*)d_out;

  char* ws = (char*)d_ws;
  size_t off = 0;
  auto alloc = [&](size_t bytes) -> void* {
    void* p = ws + off;
    off += (bytes + 255) & ~(size_t)255;
    return p;
  };
  u16*   xb     = (u16*)alloc((size_t)T_TOK * DM * 2);        // 8 MB
  u16*   B1cat  = (u16*)alloc((size_t)NCAT * DM * 2);         // 40 MB  rows: [8*2048 expert | 4096 shared]
  u16*   B3cat  = (u16*)alloc((size_t)NCAT * DM * 2);         // 40 MB
  u16*   W2catT = (u16*)alloc((size_t)DM * NCAT * 2);         // 40 MB  [1024][20480]
  float* comb   = (float*)alloc((size_t)T_TOK * NE * 4);      // 128 KB
  float* bias1  = (float*)alloc((size_t)NCAT * 4);            // 80 KB  (b1 cat bs1)
  float* bias3  = (float*)alloc((size_t)NCAT * 4);            // 80 KB
  const size_t fixed = off;

  // act + partial chunked over T to fit ws
  const size_t perTok = (size_t)NCAT * 2 + (size_t)KSPLIT * DM * 4;   // 61440 B/token
  int chunkT = T_TOK;
  while (chunkT > 512 && fixed + (size_t)chunkT * perTok > ws_size) chunkT >>= 1;
  if (fixed + (size_t)chunkT * perTok > ws_size) return;   // clean fail, no OOB
  u16*   act     = (u16*)alloc((size_t)chunkT * NCAT * 2);
  float* partial = (float*)alloc((size_t)KSPLIT * chunkT * DM * 4);

  // ---- input conversion + gating (exact fp32) ----
  cvt_bf16<<<(T_TOK * DM / 4 + 255) / 256, 256, 0, stream>>>(x, xb, T_TOK * DM / 4);
  gating_kernel<<<T_TOK / 4, 256, 0, stream>>>(x, Wg, comb);

  // bias concat (fp32 d2d copies)
  hipMemcpyAsync(bias1, b1, (size_t)NE * DF * 4, hipMemcpyDeviceToDevice, stream);
  hipMemcpyAsync(bias1 + NEXPCOL, bs1, (size_t)FS * 4, hipMemcpyDeviceToDevice, stream);
  hipMemcpyAsync(bias3, b3, (size_t)NE * DF * 4, hipMemcpyDeviceToDevice, stream);
  hipMemcpyAsync(bias3 + NEXPCOL, bs3, (size_t)FS * 4, hipMemcpyDeviceToDevice, stream);

  // ---- weight prep (batched) ----
  // W1[e][d][f] -> B1cat[(e*2048+f)][d]
  tconv2<<<dim3(DF / 32, DM / 32, NE), 256, 0, stream>>>(W1, B1cat, DM, DF, DM, DF, 0);
  tconv2<<<dim3(DF / 32, DM / 32, NE), 256, 0, stream>>>(W3, B3cat, DM, DF, DM, DF, 0);
  // Ws1[d][fs] -> B1cat[(16384+fs)][d]
  tconv2<<<dim3(FS / 32, DM / 32, 1), 256, 0, stream>>>(Ws1, B1cat + (size_t)NEXPCOL * DM,
                                                        DM, FS, DM, 0, 0);
  tconv2<<<dim3(FS / 32, DM / 32, 1), 256, 0, stream>>>(Ws3, B3cat + (size_t)NEXPCOL * DM,
                                                        DM, FS, DM, 0, 0);
  // W2[e][f][d] -> W2catT[d][e*2048+f]
  tconv2<<<dim3(DM / 32, DF / 32, NE), 256, 0, stream>>>(W2, W2catT, DF, DM, NCAT, 0, DF);
  // Ws2[fs][d] -> W2catT[d][16384+fs]
  tconv2<<<dim3(DM / 32, FS / 32, 1), 256, 0, stream>>>(Ws2, W2catT + NEXPCOL,
                                                        FS, DM, NCAT, 0, 0);

  // ---- main pipeline, chunked over T ----
  const dim3 gUp(NCAT / 128, chunkT / 128);          // 160 x (chunkT/128)
  const dim3 gDn(DM / 128, chunkT / 128, KSPLIT);    //   8 x (chunkT/128) x 5
  const int  nred = chunkT * DM / 4;
  for (int tc = 0; tc < T_TOK; tc += chunkT) {
    gemm_up_silu<<<gUp, 256, 0, stream>>>(xb + (size_t)tc * DM, B1cat, B3cat,
                                          bias1, bias3, comb + (size_t)tc * NE, act);
    gemm_down<<<gDn, 256, 0, stream>>>(act, W2catT, partial, chunkT);
    reduce_down<<<(nred + 255) / 256, 256, 0, stream>>>(partial, out + (size_t)tc * DM,
                                                        comb + (size_t)tc * NE, b2, bs2,
                                                        chunkT);
  }
}

// Round 5
// 1019.533 us; speedup vs baseline: 1.5486x; 1.5486x over previous
//
#include <hip/hip_runtime.h>
#include <hip/hip_bf16.h>
#include <cstdint>
#include <cstddef>

// Problem constants (from reference)
#define T_TOK 4096
#define DM    1024
#define DF    2048
#define FS    4096
#define NE    8
#define NCAT    20480   // 8*2048 expert cols + 4096 shared cols
#define NEXPCOL 16384   // boundary: cols < this are expert cols
#define KSPLIT  5       // down-GEMM K split (NCAT/KSPLIT = 4096)
#define KCH     4096

typedef __attribute__((ext_vector_type(8))) short          s16x8;  // 8 x bf16
typedef __attribute__((ext_vector_type(8))) unsigned short u16x8;
typedef __attribute__((ext_vector_type(4))) float          f32x4;
typedef unsigned short u16;

// ---------------- helpers ----------------
__device__ __forceinline__ u16 f2bf(float f) {
  unsigned u = __builtin_bit_cast(unsigned, f);
  unsigned r = u + 0x7fffu + ((u >> 16) & 1u);   // RNE
  return (u16)(r >> 16);
}

__device__ __forceinline__ float silu_prod(float a, float b) {
  float z = a * b;
  return z / (1.f + __expf(-z));
}

__device__ __forceinline__ void load_lds16(const u16* g, u16* l) {
  __builtin_amdgcn_global_load_lds(
      (const __attribute__((address_space(1))) unsigned int*)g,
      (__attribute__((address_space(3))) unsigned int*)l,
      16, 0, 0);
}

// ---------------- x -> bf16 ----------------
__global__ __launch_bounds__(256) void cvt_bf16(const float* __restrict__ in,
                                                u16* __restrict__ out, int n4) {
  int i = blockIdx.x * 256 + threadIdx.x;
  if (i >= n4) return;
  float4 v = ((const float4*)in)[i];
  ushort4 o;
  o.x = f2bf(v.x); o.y = f2bf(v.y); o.z = f2bf(v.z); o.w = f2bf(v.w);
  ((ushort4*)out)[i] = o;
}

// ---------------- unified weight transpose+convert, single launch ----------------
// For each descriptor: in[z][R][C] f32 -> out[(c + z*zr)*ldo + z*zc + r] bf16.
// 64x64 tiles, one block per tile.
struct TD { const float* in; u16* out; int R, C, ldo, zr, zc, start; };
struct TD6 { TD d[6]; };

__global__ __launch_bounds__(256) void wtconv(TD6 P) {
  __shared__ float tile[64][65];     // 65 stride: odd -> conflict-free (65 mod 32 = 1)
  const int bid = blockIdx.x;
  int sel = 0;
#pragma unroll
  for (int k = 1; k < 6; k++) if (bid >= P.d[k].start) sel = k;
  const TD D = P.d[sel];

  const int lb  = bid - D.start;
  const int ct  = D.C >> 6;          // tiles along C
  const int rt  = D.R >> 6;
  const int tpz = ct * rt;
  const int z   = lb / tpz;
  const int rem = lb - z * tpz;
  const int tr  = rem / ct;
  const int tc  = rem - tr * ct;

  const float* in = D.in + (size_t)z * D.R * D.C + ((size_t)(tr << 6)) * D.C + (tc << 6);
  const int t = threadIdx.x;

  {  // load 64x64 f32: lane r = t>>2, col block 16*(t&3); 4x float4 each
    const int r  = t >> 2;
    const int c0 = (t & 3) << 4;
    const float* src = in + (size_t)r * D.C + c0;
    float4 v0 = *(const float4*)(src + 0);
    float4 v1 = *(const float4*)(src + 4);
    float4 v2 = *(const float4*)(src + 8);
    float4 v3 = *(const float4*)(src + 12);
    float* tl = &tile[r][c0];
    tl[0]  = v0.x; tl[1]  = v0.y; tl[2]  = v0.z; tl[3]  = v0.w;
    tl[4]  = v1.x; tl[5]  = v1.y; tl[6]  = v1.z; tl[7]  = v1.w;
    tl[8]  = v2.x; tl[9]  = v2.y; tl[10] = v2.z; tl[11] = v2.w;
    tl[12] = v3.x; tl[13] = v3.y; tl[14] = v3.z; tl[15] = v3.w;
  }
  __syncthreads();
  {  // transposed read: lane handles out-row c = t>>2, in-rows 16*(t&3)..+16
    const int c  = t >> 2;
    const int r0 = (t & 3) << 4;
    u16x8 a, b;
#pragma unroll
    for (int j = 0; j < 8; j++) a[j] = f2bf(tile[r0 + j][c]);
#pragma unroll
    for (int j = 0; j < 8; j++) b[j] = f2bf(tile[r0 + 8 + j][c]);
    u16* dst = D.out + (size_t)((tc << 6) + c + (size_t)z * D.zr) * D.ldo
                     + (size_t)z * D.zc + (tr << 6) + r0;
    *(u16x8*)(dst + 0) = a;
    *(u16x8*)(dst + 8) = b;
  }
}

// ---------------- gating: exact fp32 softmax -> top2 -> softmax weights ----------------
__global__ __launch_bounds__(256) void gating_kernel(const float* __restrict__ x,
                                                     const float* __restrict__ Wg,
                                                     float* __restrict__ comb) {
  int t = blockIdx.x * 4 + (threadIdx.x >> 6);
  int lane = threadIdx.x & 63;
  float p[NE];
#pragma unroll
  for (int e = 0; e < NE; e++) p[e] = 0.f;
  const float* xr = x + (size_t)t * DM;
  for (int d = lane; d < DM; d += 64) {
    float xv = xr[d];
    const float* wr = Wg + (size_t)d * NE;
#pragma unroll
    for (int e = 0; e < NE; e++) p[e] += xv * wr[e];
  }
#pragma unroll
  for (int off = 32; off > 0; off >>= 1) {
#pragma unroll
    for (int e = 0; e < NE; e++) p[e] += __shfl_xor(p[e], off, 64);
  }
  if (lane == 0) {
    float m = p[0];
#pragma unroll
    for (int e = 1; e < NE; e++) m = fmaxf(m, p[e]);
    float sc[NE]; float s = 0.f;
#pragma unroll
    for (int e = 0; e < NE; e++) { sc[e] = expf(p[e] - m); s += sc[e]; }
    float inv = 1.f / s;
#pragma unroll
    for (int e = 0; e < NE; e++) sc[e] *= inv;
    // top-2, ties -> lower index (matches lax.top_k)
    int i1 = 0; float v1 = sc[0];
#pragma unroll
    for (int e = 1; e < NE; e++) if (sc[e] > v1) { v1 = sc[e]; i1 = e; }
    int i2 = -1; float v2 = -1.f;
#pragma unroll
    for (int e = 0; e < NE; e++) if (e != i1 && sc[e] > v2) { v2 = sc[e]; i2 = e; }
    // renormalize: softmax over the two selected scores
    float w2 = 1.f / (1.f + expf(v1 - v2));
    float w1 = 1.f - w2;
    float* cr = comb + (size_t)t * NE;
#pragma unroll
    for (int e = 0; e < NE; e++) cr[e] = (e == i1) ? w1 : ((e == i2) ? w2 : 0.f);
  }
}

// ---------------- fused dual up-GEMM + silu + comb-scale ----------------
// act[M x NCAT](bf16) = cw(n) * silu( (A*B1^T + b1) .* (A*B3^T + b3) )
// A:[M x 1024] bf16; B1,B3:[NCAT x 1024] bf16 row-major; cw = comb[t, n>>11] for
// n < NEXPCOL else 1.  m97 128^2-tile structure, K = 1024.
__global__ __launch_bounds__(256, 2) void gemm_up_silu(const u16* __restrict__ A,
                                                       const u16* __restrict__ B1,
                                                       const u16* __restrict__ B3,
                                                       const float* __restrict__ b1,
                                                       const float* __restrict__ bs1,
                                                       const float* __restrict__ b3,
                                                       const float* __restrict__ bs3,
                                                       const float* __restrict__ comb,
                                                       u16* __restrict__ act) {
  __shared__ u16 sA[128 * 32];
  __shared__ u16 sB1[128 * 32];
  __shared__ u16 sB3[128 * 32];
  const int K    = DM;
  const int tid  = threadIdx.x;
  const int m0   = blockIdx.y * 128;
  const int n0   = blockIdx.x * 128;
  const int lane = tid & 63;
  const int w    = tid >> 6;
  const int wr   = (w >> 1) * 64;
  const int wc   = (w & 1) * 64;
  const int fr   = lane & 15;
  const int fq   = lane >> 4;

  f32x4 acc1[4][4] = {};
  f32x4 acc3[4][4] = {};

  const int li0 = tid * 8;                  // element index in 128x32 tile
  const u16* gA0  = A  + (size_t)(m0 + (li0 >> 5)) * K + (li0 & 31);
  const u16* gB10 = B1 + (size_t)(n0 + (li0 >> 5)) * K + (li0 & 31);
  const u16* gB30 = B3 + (size_t)(n0 + (li0 >> 5)) * K + (li0 & 31);
  const size_t rowskip = (size_t)64 * K;    // chunk1 = +64 rows
  u16* lA0  = sA  + ((tid & 192) << 3);     // wave-uniform LDS base
  u16* lB10 = sB1 + ((tid & 192) << 3);
  u16* lB30 = sB3 + ((tid & 192) << 3);

  for (int k0 = 0; k0 < K; k0 += 32) {
    load_lds16(gA0  + k0,           lA0);
    load_lds16(gA0  + k0 + rowskip, lA0 + 2048);
    load_lds16(gB10 + k0,           lB10);
    load_lds16(gB10 + k0 + rowskip, lB10 + 2048);
    load_lds16(gB30 + k0,           lB30);
    load_lds16(gB30 + k0 + rowskip, lB30 + 2048);
    __syncthreads();

    s16x8 af[4], b1f[4], b3f[4];
#pragma unroll
    for (int m = 0; m < 4; m++)
      af[m] = *(const s16x8*)(sA + (wr + m * 16 + fr) * 32 + fq * 8);
#pragma unroll
    for (int n = 0; n < 4; n++) {
      b1f[n] = *(const s16x8*)(sB1 + (wc + n * 16 + fr) * 32 + fq * 8);
      b3f[n] = *(const s16x8*)(sB3 + (wc + n * 16 + fr) * 32 + fq * 8);
    }
#pragma unroll
    for (int m = 0; m < 4; m++)
#pragma unroll
      for (int n = 0; n < 4; n++) {
        acc1[m][n] = __builtin_amdgcn_mfma_f32_16x16x32_bf16(af[m], b1f[n], acc1[m][n], 0, 0, 0);
        acc3[m][n] = __builtin_amdgcn_mfma_f32_16x16x32_bf16(af[m], b3f[n], acc3[m][n], 0, 0, 0);
      }
    __syncthreads();
  }

  // expert id for this column block (128-tile never straddles a 2048 boundary)
  const bool isExp = (n0 < NEXPCOL);
  const int  eid   = n0 >> 11;

  // C/D layout (m89-verified): col = lane&15, row = (lane>>4)*4 + j
#pragma unroll
  for (int m = 0; m < 4; m++) {
#pragma unroll
    for (int n = 0; n < 4; n++) {
      int cc = n0 + wc + n * 16 + fr;
      float c1 = isExp ? b1[cc] : bs1[cc - NEXPCOL];
      float c3 = isExp ? b3[cc] : bs3[cc - NEXPCOL];
#pragma unroll
      for (int j = 0; j < 4; j++) {
        int r = m0 + wr + m * 16 + fq * 4 + j;
        float wgt = isExp ? comb[(size_t)r * NE + eid] : 1.f;
        float v = wgt * silu_prod(acc1[m][n][j] + c1, acc3[m][n][j] + c3);
        act[(size_t)r * NCAT + cc] = f2bf(v);
      }
    }
  }
}

// ---------------- down GEMM, K-split ----------------
// partial[z][M x 1024] = A[M x NCAT](cols z*4096..+4096) * B^T(same K range)
__global__ __launch_bounds__(256, 2) void gemm_down(const u16* __restrict__ A,
                                                    const u16* __restrict__ B,
                                                    float* __restrict__ partial,
                                                    int Mchunk) {
  __shared__ u16 sA[128 * 32];
  __shared__ u16 sB[128 * 32];
  const int tid  = threadIdx.x;
  const int m0   = blockIdx.y * 128;
  const int n0   = blockIdx.x * 128;
  const int z    = blockIdx.z;
  const int lane = tid & 63;
  const int w    = tid >> 6;
  const int wr   = (w >> 1) * 64;
  const int wc   = (w & 1) * 64;
  const int fr   = lane & 15;
  const int fq   = lane >> 4;

  f32x4 acc[4][4] = {};

  const int li0 = tid * 8;
  const size_t zoff = (size_t)z * KCH;
  const u16* gA0 = A + (size_t)(m0 + (li0 >> 5)) * NCAT + zoff + (li0 & 31);
  const u16* gB0 = B + (size_t)(n0 + (li0 >> 5)) * NCAT + zoff + (li0 & 31);
  const size_t rowskip = (size_t)64 * NCAT;
  u16* lA0 = sA + ((tid & 192) << 3);
  u16* lB0 = sB + ((tid & 192) << 3);

  for (int k0 = 0; k0 < KCH; k0 += 32) {
    load_lds16(gA0 + k0,           lA0);
    load_lds16(gA0 + k0 + rowskip, lA0 + 2048);
    load_lds16(gB0 + k0,           lB0);
    load_lds16(gB0 + k0 + rowskip, lB0 + 2048);
    __syncthreads();

    s16x8 af[4], bfr[4];
#pragma unroll
    for (int m = 0; m < 4; m++)
      af[m] = *(const s16x8*)(sA + (wr + m * 16 + fr) * 32 + fq * 8);
#pragma unroll
    for (int n = 0; n < 4; n++)
      bfr[n] = *(const s16x8*)(sB + (wc + n * 16 + fr) * 32 + fq * 8);
#pragma unroll
    for (int m = 0; m < 4; m++)
#pragma unroll
      for (int n = 0; n < 4; n++)
        acc[m][n] = __builtin_amdgcn_mfma_f32_16x16x32_bf16(af[m], bfr[n], acc[m][n], 0, 0, 0);
    __syncthreads();
  }

  float* P = partial + (size_t)z * Mchunk * DM;
#pragma unroll
  for (int m = 0; m < 4; m++) {
#pragma unroll
    for (int n = 0; n < 4; n++) {
      int cc = n0 + wc + n * 16 + fr;
#pragma unroll
      for (int j = 0; j < 4; j++) {
        int r = m0 + wr + m * 16 + fq * 4 + j;
        P[(size_t)r * DM + cc] = acc[m][n][j];
      }
    }
  }
}

// ---------------- reduce partials + gated bias ----------------
// out[t][d] = sum_z partial[z][tl][d] + sum_e comb[t,e]*b2[e,d] + bs2[d]
__global__ __launch_bounds__(256) void reduce_down(const float* __restrict__ partial,
                                                   float* __restrict__ out,
                                                   const float* __restrict__ comb,
                                                   const float* __restrict__ b2,
                                                   const float* __restrict__ bs2,
                                                   int Mchunk) {
  int i = blockIdx.x * 256 + threadIdx.x;         // float4 index over Mchunk*DM/4
  if (i >= Mchunk * (DM / 4)) return;
  int tl = i / (DM / 4);
  int d4 = (i % (DM / 4)) * 4;
  const size_t stride = (size_t)Mchunk * DM;
  float4 s = ((const float4*)partial)[i];
#pragma unroll
  for (int z = 1; z < KSPLIT; z++) {
    float4 p = *(const float4*)(partial + (size_t)z * stride + (size_t)tl * DM + d4);
    s.x += p.x; s.y += p.y; s.z += p.z; s.w += p.w;
  }
  float4 bsh = *(const float4*)(bs2 + d4);
  s.x += bsh.x; s.y += bsh.y; s.z += bsh.z; s.w += bsh.w;
  const float* cr = comb + (size_t)tl * NE;
#pragma unroll
  for (int e = 0; e < NE; e++) {
    float cw = cr[e];
    float4 bb = *(const float4*)(b2 + (size_t)e * DM + d4);
    s.x += cw * bb.x; s.y += cw * bb.y; s.z += cw * bb.z; s.w += cw * bb.w;
  }
  ((float4*)out)[i] = s;
}

// ---------------- host ----------------
extern "C" void kernel_launch(void* const* d_in, const int* in_sizes, int n_in,
                              void* d_out, int out_size, void* d_ws, size_t ws_size,
                              hipStream_t stream) {
  const float* x   = (const float*)d_in[0];
  const float* Wg  = (const float*)d_in[1];
  const float* W1  = (const float*)d_in[2];
  const float* b1  = (const float*)d_in[3];
  const float* W3  = (const float*)d_in[4];
  const float* b3  = (const float*)d_in[5];
  const float* W2  = (const float*)d_in[6];
  const float* b2  = (const float*)d_in[7];
  const float* Ws1 = (const float*)d_in[8];
  const float* bs1 = (const float*)d_in[9];
  const float* Ws3 = (const float*)d_in[10];
  const float* bs3 = (const float*)d_in[11];
  const float* Ws2 = (const float*)d_in[12];
  const float* bs2 = (const float*)d_in[13];
  float* out = (float*)d_out;

  char* ws = (char*)d_ws;
  size_t off = 0;
  auto alloc = [&](size_t bytes) -> void* {
    void* p = ws + off;
    off += (bytes + 255) & ~(size_t)255;
    return p;
  };
  u16*   xb     = (u16*)alloc((size_t)T_TOK * DM * 2);        // 8 MB
  u16*   B1cat  = (u16*)alloc((size_t)NCAT * DM * 2);         // 40 MB  rows: [8*2048 expert | 4096 shared]
  u16*   B3cat  = (u16*)alloc((size_t)NCAT * DM * 2);         // 40 MB
  u16*   W2catT = (u16*)alloc((size_t)DM * NCAT * 2);         // 40 MB  [1024][20480]
  float* comb   = (float*)alloc((size_t)T_TOK * NE * 4);      // 128 KB
  const size_t fixed = off;

  // act + partial chunked over T to fit ws
  const size_t perTok = (size_t)NCAT * 2 + (size_t)KSPLIT * DM * 4;   // 61440 B/token
  int chunkT = T_TOK;
  while (chunkT > 512 && fixed + (size_t)chunkT * perTok > ws_size) chunkT >>= 1;
  if (fixed + (size_t)chunkT * perTok > ws_size) return;   // clean fail, no OOB
  u16*   act     = (u16*)alloc((size_t)chunkT * NCAT * 2);
  float* partial = (float*)alloc((size_t)KSPLIT * chunkT * DM * 4);

  // ---- input conversion + gating (exact fp32) ----
  cvt_bf16<<<(T_TOK * DM / 4 + 255) / 256, 256, 0, stream>>>(x, xb, T_TOK * DM / 4);
  gating_kernel<<<T_TOK / 4, 256, 0, stream>>>(x, Wg, comb);

  // ---- unified weight prep: one launch, 64x64 tile per block ----
  // tile counts: W1 4096, W3 4096, W2 4096, Ws1 1024, Ws3 1024, Ws2 1024
  TD6 P;
  P.d[0] = { W1,  B1cat,                        DM, DF, DM,   DF, 0,  0     };
  P.d[1] = { W3,  B3cat,                        DM, DF, DM,   DF, 0,  4096  };
  P.d[2] = { W2,  W2catT,                       DF, DM, NCAT, 0,  DF, 8192  };
  P.d[3] = { Ws1, B1cat + (size_t)NEXPCOL * DM, DM, FS, DM,   0,  0,  12288 };
  P.d[4] = { Ws3, B3cat + (size_t)NEXPCOL * DM, DM, FS, DM,   0,  0,  13312 };
  P.d[5] = { Ws2, W2catT + NEXPCOL,             FS, DM, NCAT, 0,  0,  14336 };
  wtconv<<<15360, 256, 0, stream>>>(P);

  // ---- main pipeline, chunked over T ----
  const dim3 gUp(NCAT / 128, chunkT / 128);          // 160 x (chunkT/128)
  const dim3 gDn(DM / 128, chunkT / 128, KSPLIT);    //   8 x (chunkT/128) x 5
  const int  nred = chunkT * DM / 4;
  for (int tc = 0; tc < T_TOK; tc += chunkT) {
    gemm_up_silu<<<gUp, 256, 0, stream>>>(xb + (size_t)tc * DM, B1cat, B3cat,
                                          b1, bs1, b3, bs3,
                                          comb + (size_t)tc * NE, act);
    gemm_down<<<gDn, 256, 0, stream>>>(act, W2catT, partial, chunkT);
    reduce_down<<<(nred + 255) / 256, 256, 0, stream>>>(partial, out + (size_t)tc * DM,
                                                        comb + (size_t)tc * NE, b2, bs2,
                                                        chunkT);
  }
}